// Round 15
// baseline (196.854 us; speedup 1.0000x reference)
//
#include <hip/hip_runtime.h>
#include <hip/hip_bf16.h>
#include <stdint.h>

#define M_DIM 8192
#define N_DIM 4096
#define K_DIM 4096

typedef __attribute__((ext_vector_type(4))) int   int4v;
typedef __attribute__((ext_vector_type(4))) float floatx4;

// ---------------- pre-pass 1: per-row quantize x f32 -> i8, scale = rowmax/127 -------
__global__ __launch_bounds__(256) void quant_x_kernel(const float* __restrict__ x,
                                                      signed char* __restrict__ xq,
                                                      float* __restrict__ xs) {
    const int row = blockIdx.x;
    const int tid = threadIdx.x;
    const int wave = tid >> 6, lane = tid & 63;
    const float4* xr = (const float4*)(x + (size_t)row * K_DIM);

    float4 v[4];
    float m = 0.f;
    #pragma unroll
    for (int j = 0; j < 4; ++j) {
        v[j] = xr[j * 256 + tid];
        m = fmaxf(m, fmaxf(fmaxf(fabsf(v[j].x), fabsf(v[j].y)),
                           fmaxf(fabsf(v[j].z), fabsf(v[j].w))));
    }
    #pragma unroll
    for (int off = 32; off >= 1; off >>= 1) m = fmaxf(m, __shfl_down(m, off));
    __shared__ float wm_s[4];
    if (lane == 0) wm_s[wave] = m;
    __syncthreads();
    const float M = fmaxf(fmaxf(wm_s[0], wm_s[1]), fmaxf(wm_s[2], wm_s[3]));
    const float inv = M > 0.f ? 127.f / M : 0.f;
    if (tid == 0) xs[row] = M > 0.f ? M / 127.f : 0.f;

    char4* xo = (char4*)(xq + (size_t)row * K_DIM);
    #pragma unroll
    for (int j = 0; j < 4; ++j) {
        char4 q;
        q.x = (signed char)__float2int_rn(v[j].x * inv);
        q.y = (signed char)__float2int_rn(v[j].y * inv);
        q.z = (signed char)__float2int_rn(v[j].z * inv);
        q.w = (signed char)__float2int_rn(v[j].w * inv);
        xo[j * 256 + tid] = q;
    }
}

// ------- pre-pass 2: w f32 [K][N] -> sign(w) i8 transposed [N][K] (LDS transpose) ----
__global__ __launch_bounds__(256) void cvt_w_kernel(const float* __restrict__ w,
                                                    signed char* __restrict__ wT) {
    __shared__ signed char tile[64][68];   // pad breaks pow2 column-read stride
    const int t  = threadIdx.x;
    const int k0 = blockIdx.y * 64;
    const int n0 = blockIdx.x * 64;
    #pragma unroll
    for (int p = 0; p < 4; ++p) {
        int kk = p * 16 + (t >> 4);
        int nn = (t & 15) * 4;
        float4 v = *reinterpret_cast<const float4*>(&w[(size_t)(k0 + kk) * N_DIM + n0 + nn]);
        tile[kk][nn + 0] = v.x > 0.f ? 1 : (v.x < 0.f ? -1 : 0);
        tile[kk][nn + 1] = v.y > 0.f ? 1 : (v.y < 0.f ? -1 : 0);
        tile[kk][nn + 2] = v.z > 0.f ? 1 : (v.z < 0.f ? -1 : 0);
        tile[kk][nn + 3] = v.w > 0.f ? 1 : (v.w < 0.f ? -1 : 0);
    }
    __syncthreads();
    const int r = t >> 2;          // local n row
    const int c = (t & 3) * 16;    // local k byte
    int4v o;
    signed char* op = (signed char*)&o;
    #pragma unroll
    for (int j = 0; j < 16; ++j) op[j] = tile[c + j][r];
    *reinterpret_cast<int4v*>(&wT[(size_t)(n0 + r) * K_DIM + k0 + c]) = o;
}

// =====================================================================================
// 128x256 i8 GEMM blocks, 512 threads / 8 waves (2M x 4N, 64x64 per wave),
// TWO INDEPENDENT BLOCKS PER CU (LDS 72 KB, VGPR ~56):
//   C = relu( xs[row] * (Xq * signW^T) + bias )
// Anti-phasing mechanism: the two co-resident blocks have independent barriers, so
// one block's ds_read burst overlaps the other block's MFMA burst on the CU pipes.
// r11's proven staging: 3 LDS slots/operand, staged TWO tiles ahead, 1 barrier/tile.
// LDS: As[3][128*64] (24 KiB) + Bs[3][256*64] (48 KiB) = 72 KiB.
// Swizzle f(row)=((row>>1)&3)<<4 (verified 0-conflict, half-wave floor).
// Per tile t: 8 ds_reads ; stage {A,B}(t+2) (3 GLD: A x1, B x2) ; 16 MFMA ;
//             vmcnt(3) ; barrier.
// vmcnt ledger: outstanding at tile end = {A,B}(t+1)x3 (issued t-1) + {A,B}(t+2)x3
// (issued t) = 6; vmcnt(3) retires the t+1 triple -- issued a full tile ago, no stall.
// =====================================================================================
#define BM 128
#define BN 256
#define BK 64
#define NT (K_DIM / BK)

#define GLD(gsrc, ldst) __builtin_amdgcn_global_load_lds( \
    (const __attribute__((address_space(1))) unsigned int*)(gsrc), \
    (__attribute__((address_space(3))) unsigned int*)(ldst), 16, 0, 0)

__global__ __launch_bounds__(512, 4) void gemm_i8_kernel(
    const signed char* __restrict__ A,   // [M][K] i8 (quantized x)
    const signed char* __restrict__ BT,  // [N][K] i8 = sign(w)^T
    const float* __restrict__ xsc,       // [M] row scales
    const float* __restrict__ bias,
    float* __restrict__ C)               // [M][N] f32
{
    __shared__ signed char As[3][128 * 64];   // 24 KiB
    __shared__ signed char Bs[3][256 * 64];   // 48 KiB

    const int tid  = threadIdx.x;
    const int wave = tid >> 6;
    const int lane = tid & 63;
    const int wm   = wave >> 2;        // 0..1 : wave M-slot (rows wm*64..+63)
    const int wn   = wave & 3;         // 0..3 : wave N-slot (cols wn*64..+63)

    // XCD-bijective swizzle (nwg = 1024, divisible by 8)
    const int bid  = blockIdx.x;
    const int sbid = (bid & 7) * 128 + (bid >> 3);
    const int tn   = sbid & 15;        // N_DIM/BN = 16
    const int tm   = sbid >> 4;        // M_DIM/BM = 64
    const int bm   = tm * BM;
    const int bn   = tn * BN;

    // staging (write side of swizzle): dest linear o = tid*16; row = tid>>2 (+128/sweep);
    // source col = ((tid&3) ^ ((tid>>3)&3)) * 16   [row bits 2:1 = tid bits 4:3]
    const int srow = tid >> 2;
    const int scol = ((tid & 3) ^ ((tid >> 3) & 3)) * 16;

    // fragment read offsets (read side of swizzle)
    const int laneRow = (lane & 15) * 64;
    const int colX = ((lane >> 4) * 16) ^ (((lane >> 1) & 3) << 4);
    const int Abase = wm * 64 * 64;    // wave's A row base (bytes)
    const int Bbase = wn * 64 * 64;    // wave's B row base (bytes)

    int4v acc[4][4] = {};              // 64 VGPRs: 4x4 of 16x16 frags = 64x64

#define STAGE_A(KOFS, SLOT) do { \
    GLD(A + (size_t)(bm + srow) * K_DIM + (KOFS) + scol, As[SLOT] + wave * 1024); \
  } while (0)
#define STAGE_B(KOFS, SLOT) do { \
    GLD(BT + (size_t)(bn + srow) * K_DIM + (KOFS) + scol, Bs[SLOT] + wave * 1024); \
    GLD(BT + (size_t)(bn + 128 + srow) * K_DIM + (KOFS) + scol, \
        Bs[SLOT] + 8192 + wave * 1024); \
  } while (0)

    // ---- prologue: stage tiles 0,1 -> slots 0,1; retire tile-0 triple, keep tile-1 ----
    STAGE_A(0,  0);
    STAGE_B(0,  0);
    STAGE_A(BK, 1);
    STAGE_B(BK, 1);
    asm volatile("s_waitcnt vmcnt(3)" ::: "memory");
    __builtin_amdgcn_s_barrier();

    int4v a[4];    // A frags (reused per tile)
    int4v b[4];    // B frags

    int rd = 0;    // t % 3
    int st = 2;    // (t+2) % 3

    for (int t = 0; t < NT; ++t) {
        const char* Ar = (const char*)As[rd];
        const char* Br = (const char*)Bs[rd];
        const int kS = (t + 2 < NT ? t + 2 : NT - 1) * BK;   // tail reloads never read

        // ---- 8 ds_reads, consumption order ----
        a[0] = *(const int4v*)(Ar + Abase + (0*16)*64 + laneRow + colX);
        b[0] = *(const int4v*)(Br + Bbase + (0*16)*64 + laneRow + colX);
        b[1] = *(const int4v*)(Br + Bbase + (1*16)*64 + laneRow + colX);
        b[2] = *(const int4v*)(Br + Bbase + (2*16)*64 + laneRow + colX);
        b[3] = *(const int4v*)(Br + Bbase + (3*16)*64 + laneRow + colX);
        a[1] = *(const int4v*)(Ar + Abase + (1*16)*64 + laneRow + colX);
        a[2] = *(const int4v*)(Ar + Abase + (2*16)*64 + laneRow + colX);
        a[3] = *(const int4v*)(Ar + Abase + (3*16)*64 + laneRow + colX);

        // ---- stage {A,B}(t+2) into slot (t+2)%3 (readers ran in tile t-1) ----
        STAGE_A(kS, st);
        STAGE_B(kS, st);

        // ---- 16 MFMA (compiler-counted lgkm waits interleave with reads) ----
        __builtin_amdgcn_s_setprio(1);
        #pragma unroll
        for (int mf = 0; mf < 4; ++mf)
            #pragma unroll
            for (int nf = 0; nf < 4; ++nf)
                acc[mf][nf] = __builtin_amdgcn_mfma_i32_16x16x64_i8(
                    a[mf], b[nf], acc[mf][nf], 0, 0, 0);
        __builtin_amdgcn_s_setprio(0);

        // retire {A,B}(t+1) (issued a full tile ago); keep {A,B}(t+2) in flight
        asm volatile("s_waitcnt vmcnt(3)" ::: "memory");
        __builtin_amdgcn_s_barrier();

        rd = (rd == 2) ? 0 : rd + 1;
        st = (st == 2) ? 0 : st + 1;
    }

    // ---- epilogue: dequant (per-row scale) + bias + relu, f32 store ----
    float bv[4];
    #pragma unroll
    for (int nf = 0; nf < 4; ++nf)
        bv[nf] = bias[bn + wn * 64 + nf * 16 + (lane & 15)];
    #pragma unroll
    for (int mf = 0; mf < 4; ++mf) {
        const int row0 = bm + wm * 64 + mf * 16 + (lane >> 4) * 4;
        float sr[4];
        #pragma unroll
        for (int r = 0; r < 4; ++r) sr[r] = xsc[row0 + r];
        #pragma unroll
        for (int nf = 0; nf < 4; ++nf) {
            const int col = bn + wn * 64 + nf * 16 + (lane & 15);
            float* cp = C + (size_t)row0 * N_DIM + col;
            #pragma unroll
            for (int r = 0; r < 4; ++r) {
                float v = (float)acc[mf][nf][r] * sr[r] + bv[nf];
                cp[(size_t)r * N_DIM] = v > 0.f ? v : 0.f;
            }
        }
    }
}

// ---------------- fallback (only if ws_size too small): naive tiled fp32 -------------
__global__ void naive_kernel(const float* __restrict__ x, const float* __restrict__ w,
                             const float* __restrict__ b, float* __restrict__ out) {
    __shared__ float xs[16][16];
    __shared__ float ws[16][17];
    const int row = blockIdx.y * 16 + threadIdx.y;
    const int col = blockIdx.x * 16 + threadIdx.x;
    float acc = 0.f;
    for (int k0 = 0; k0 < K_DIM; k0 += 16) {
        xs[threadIdx.y][threadIdx.x] = x[(size_t)row * K_DIM + k0 + threadIdx.x];
        float wv = w[(size_t)(k0 + threadIdx.y) * N_DIM + col];
        ws[threadIdx.y][threadIdx.x] = wv > 0.f ? 1.f : (wv < 0.f ? -1.f : 0.f);
        __syncthreads();
        #pragma unroll
        for (int kk = 0; kk < 16; ++kk) acc += xs[threadIdx.y][kk] * ws[kk][threadIdx.x];
        __syncthreads();
    }
    float v = acc + b[col];
    out[(size_t)row * N_DIM + col] = v > 0.f ? v : 0.f;
}

extern "C" void kernel_launch(void* const* d_in, const int* in_sizes, int n_in,
                              void* d_out, int out_size, void* d_ws, size_t ws_size,
                              hipStream_t stream) {
    const float* x = (const float*)d_in[0];
    const float* w = (const float*)d_in[1];
    const float* b = (const float*)d_in[2];
    float* out = (float*)d_out;

    const size_t xq_bytes = (size_t)M_DIM * K_DIM;                 // 32 MiB i8
    const size_t wT_bytes = (size_t)K_DIM * N_DIM;                 // 16 MiB i8
    const size_t xs_bytes = (size_t)M_DIM * sizeof(float);         // 32 KiB

    if (ws_size >= xq_bytes + wT_bytes + xs_bytes) {
        signed char* xq = (signed char*)d_ws;
        signed char* wT = (signed char*)((char*)d_ws + xq_bytes);
        float*       xs = (float*)((char*)d_ws + xq_bytes + wT_bytes);
        quant_x_kernel<<<M_DIM, 256, 0, stream>>>(x, xq, xs);
        cvt_w_kernel<<<dim3(N_DIM / 64, K_DIM / 64), 256, 0, stream>>>(w, wT);
        gemm_i8_kernel<<<(M_DIM / BM) * (N_DIM / BN), 512, 0, stream>>>(xq, wT, xs, b, out);
    } else {
        naive_kernel<<<dim3(N_DIM / 16, M_DIM / 16), dim3(16, 16), 0, stream>>>(x, w, b, out);
    }
}